// Round 1
// baseline (1921.419 us; speedup 1.0000x reference)
//
#include <hip/hip_runtime.h>
#include <hip/hip_bf16.h>

#define NR 12288
#define DIMS 256
#define NCHUNK 8
#define CW (NR / NCHUNK)   // 1536
#define BM 64
#define TOPP 9

typedef __attribute__((ext_vector_type(8))) short short8v;
typedef __attribute__((ext_vector_type(4))) float f32x4;

__device__ __forceinline__ unsigned short f2bf(float f) {
    unsigned int u = __float_as_uint(f);
    u += 0x7fffu + ((u >> 16) & 1u);   // round-to-nearest-even
    return (unsigned short)(u >> 16);
}

// Maintain the 9 largest seen. Static indexing only (rule #20): replace-min via
// unrolled scan, then rescan for new min.
__device__ __forceinline__ void top9_insert(float (&a)[9], float& mn, float v) {
    if (v > mn) {
        bool done = false;
#pragma unroll
        for (int k = 0; k < 9; ++k) {
            bool hit = (!done) && (a[k] == mn);
            if (hit) a[k] = v;
            done = done || hit;
        }
        float m = a[0];
#pragma unroll
        for (int k = 1; k < 9; ++k) m = fminf(m, a[k]);
        mn = m;
    }
}

// ---------- 1) row-normalize fp32 -> bf16, one row per wave ----------
__global__ void k_norm(const float* __restrict__ x, unsigned short* __restrict__ emb) {
    const int wave = threadIdx.x >> 6, lane = threadIdx.x & 63;
    const int row = blockIdx.x * 4 + wave;
    const float4 v = *(const float4*)(x + (size_t)row * DIMS + lane * 4);
    float ss = v.x * v.x + v.y * v.y + v.z * v.z + v.w * v.w;
#pragma unroll
    for (int off = 32; off > 0; off >>= 1) ss += __shfl_xor(ss, off);
    const float inv = 1.0f / fmaxf(sqrtf(ss), 1e-12f);
    ushort4 o;
    o.x = f2bf(v.x * inv); o.y = f2bf(v.y * inv);
    o.z = f2bf(v.z * inv); o.w = f2bf(v.w * inv);
    *(ushort4*)(emb + (size_t)row * DIMS + lane * 4) = o;
}

// ---------- 2) GEMM pass 1: per-row top-9 over a column chunk ----------
__global__ __launch_bounds__(256) void k_pass1(const unsigned short* __restrict__ emb,
                                               float* __restrict__ t9p) {
    const int wave = threadIdx.x >> 6, lane = threadIdx.x & 63;
    const int l15 = lane & 15, lg = lane >> 4;
    const int R0 = blockIdx.x * BM + wave * 16;

    // A fragments: 16 rows x 256 K held in registers for the whole sweep.
    short8v aF[8];
    const unsigned short* abase = emb + (size_t)(R0 + l15) * DIMS + lg * 8;
#pragma unroll
    for (int kk = 0; kk < 8; ++kk) aF[kk] = *(const short8v*)(abase + kk * 32);

    float t9[4][9];
    float tmin[4];
#pragma unroll
    for (int r = 0; r < 4; ++r) {
        tmin[r] = -3e38f;
#pragma unroll
        for (int k = 0; k < 9; ++k) t9[r][k] = -3e38f;
    }

    const int Cb = blockIdx.y * CW;
    for (int ct = 0; ct < CW / 16; ++ct) {
        const unsigned short* bbase = emb + (size_t)(Cb + ct * 16 + l15) * DIMS + lg * 8;
        f32x4 acc = {0.f, 0.f, 0.f, 0.f};
#pragma unroll
        for (int kk = 0; kk < 8; ++kk) {
            short8v bF = *(const short8v*)(bbase + kk * 32);
            acc = __builtin_amdgcn_mfma_f32_16x16x32_bf16(aF[kk], bF, acc, 0, 0, 0);
        }
        // C layout (m89-verified): col = lane&15, row = (lane>>4)*4 + reg
#pragma unroll
        for (int r = 0; r < 4; ++r) top9_insert(t9[r], tmin[r], acc[r]);
    }

    // merge per-row over the 16 lanes sharing that row
    __shared__ float lt9[4][64][4][9];   // 36864 B
#pragma unroll
    for (int r = 0; r < 4; ++r)
#pragma unroll
        for (int k = 0; k < 9; ++k) lt9[wave][lane][r][k] = t9[r][k];
    __syncthreads();

    if (threadIdx.x < BM) {
        const int rl = threadIdx.x;
        const int w = rl >> 4, rin = rl & 15, g = rin >> 2, reg = rin & 3;
        float best[9], bmin = -3e38f;
#pragma unroll
        for (int k = 0; k < 9; ++k) best[k] = -3e38f;
        for (int s = 0; s < 16; ++s)
#pragma unroll
            for (int k = 0; k < 9; ++k) top9_insert(best, bmin, lt9[w][g * 16 + s][reg][k]);
        float* dst = t9p + ((size_t)(blockIdx.x * BM + rl) * NCHUNK + blockIdx.y) * TOPP;
#pragma unroll
        for (int k = 0; k < 9; ++k) dst[k] = best[k];
    }
}

// ---------- 3) merge chunk top-9s -> per-row threshold (9th largest) ----------
__global__ void k_thr(const float* __restrict__ t9p, float* __restrict__ thr) {
    const int row = blockIdx.x * 256 + threadIdx.x;
    float best[9], bmin = -3e38f;
#pragma unroll
    for (int k = 0; k < 9; ++k) best[k] = -3e38f;
    const float* src = t9p + (size_t)row * NCHUNK * TOPP;
    for (int c = 0; c < NCHUNK * TOPP; ++c) top9_insert(best, bmin, src[c]);
    thr[row] = bmin;
}

// ---------- 4) GEMM pass 2 (bit-identical sim): count degrees + edge list ----------
__global__ __launch_bounds__(256) void k_pass2(const unsigned short* __restrict__ emb,
                                               const float* __restrict__ thr,
                                               unsigned* __restrict__ deg,
                                               unsigned* __restrict__ ecnt,
                                               unsigned* __restrict__ edges, unsigned ecap) {
    const int wave = threadIdx.x >> 6, lane = threadIdx.x & 63;
    const int l15 = lane & 15, lg = lane >> 4;
    const int R0 = blockIdx.x * BM + wave * 16;

    __shared__ unsigned degp[BM];
    if (threadIdx.x < BM) degp[threadIdx.x] = 0;
    __syncthreads();

    short8v aF[8];
    const unsigned short* abase = emb + (size_t)(R0 + l15) * DIMS + lg * 8;
#pragma unroll
    for (int kk = 0; kk < 8; ++kk) aF[kk] = *(const short8v*)(abase + kk * 32);

    float thr4[4];
#pragma unroll
    for (int r = 0; r < 4; ++r) thr4[r] = thr[R0 + lg * 4 + r];

    const int Cb = blockIdx.y * CW;
    for (int ct = 0; ct < CW / 16; ++ct) {
        const int C0 = Cb + ct * 16;
        const unsigned short* bbase = emb + (size_t)(C0 + l15) * DIMS + lg * 8;
        f32x4 acc = {0.f, 0.f, 0.f, 0.f};
#pragma unroll
        for (int kk = 0; kk < 8; ++kk) {
            short8v bF = *(const short8v*)(bbase + kk * 32);
            acc = __builtin_amdgcn_mfma_f32_16x16x32_bf16(aF[kk], bF, acc, 0, 0, 0);
        }
        const int cg = C0 + l15;
#pragma unroll
        for (int r = 0; r < 4; ++r) {
            const int rg = R0 + lg * 4 + r;
            if (acc[r] >= thr4[r] && cg != rg) {
                atomicAdd(&degp[wave * 16 + lg * 4 + r], 1u);
                unsigned idx = atomicAdd(ecnt, 1u);
                if (idx < ecap) edges[idx] = ((unsigned)rg << 14) | (unsigned)cg;
            }
        }
    }
    __syncthreads();
    if (threadIdx.x < BM) {
        unsigned c = degp[threadIdx.x];
        if (c) atomicAdd(&deg[blockIdx.x * BM + threadIdx.x], c);
    }
}

// ---------- 5) integer edge-weight sum (deterministic) ----------
__global__ void k_esum(const unsigned* __restrict__ deg, const unsigned* __restrict__ ecnt,
                       const unsigned* __restrict__ edges, unsigned ecap,
                       unsigned long long* __restrict__ wsum) {
    unsigned total = *ecnt;
    if (total > ecap) total = ecap;
    unsigned long long acc = 0;
    for (unsigned e = blockIdx.x * blockDim.x + threadIdx.x; e < total;
         e += gridDim.x * blockDim.x) {
        const unsigned p = edges[e];
        const unsigned i = p >> 14, j = p & 16383u;
        unsigned di = deg[i]; if (di < 1u) di = 1u;
        unsigned dj = deg[j]; if (dj < 1u) dj = 1u;
        acc += (unsigned long long)(di + dj - 2u);
    }
#pragma unroll
    for (int off = 32; off > 0; off >>= 1) acc += __shfl_xor(acc, off);
    if ((threadIdx.x & 63) == 0 && acc) atomicAdd(wsum, acc);
}

// ---------- 6) finalize ----------
__global__ void k_fin(const unsigned long long* __restrict__ wsum, float* __restrict__ out) {
    out[0] = (float)((double)*wsum * (0.01 / ((double)NR * (double)NR)));
}

extern "C" void kernel_launch(void* const* d_in, const int* in_sizes, int n_in,
                              void* d_out, int out_size, void* d_ws, size_t ws_size,
                              hipStream_t stream) {
    const float* x = (const float*)d_in[0];
    float* out = (float*)d_out;
    char* ws = (char*)d_ws;

    size_t off = 0;
    unsigned short* emb = (unsigned short*)(ws + off); off += (size_t)NR * DIMS * 2;       // 6.29 MB
    float* t9p = (float*)(ws + off);                  off += (size_t)NR * NCHUNK * TOPP * 4; // 3.54 MB
    float* thr = (float*)(ws + off);                  off += (size_t)NR * 4;
    unsigned* deg = (unsigned*)(ws + off);            off += (size_t)NR * 4;
    unsigned* ecnt = (unsigned*)(ws + off);
    unsigned long long* wsum = (unsigned long long*)(ws + off + 8);
    char* ctr = ws + off;                             off += 32;
    unsigned* edges = (unsigned*)(ws + off);
    size_t rem = (ws_size > off) ? (ws_size - off) / 4 : 0;
    unsigned ecap = rem > 2097152u ? 2097152u : (unsigned)rem;

    hipMemsetAsync(deg, 0, (size_t)NR * 4, stream);
    hipMemsetAsync(ctr, 0, 32, stream);

    k_norm<<<NR / 4, 256, 0, stream>>>(x, emb);
    k_pass1<<<dim3(NR / BM, NCHUNK), 256, 0, stream>>>(emb, t9p);
    k_thr<<<NR / 256, 256, 0, stream>>>(t9p, thr);
    k_pass2<<<dim3(NR / BM, NCHUNK), 256, 0, stream>>>(emb, thr, deg, ecnt, edges, ecap);
    k_esum<<<256, 256, 0, stream>>>(deg, ecnt, edges, ecap, wsum);
    k_fin<<<1, 1, 0, stream>>>(wsum, out);
}

// Round 2
// 1169.583 us; speedup vs baseline: 1.6428x; 1.6428x over previous
//
#include <hip/hip_runtime.h>
#include <hip/hip_bf16.h>

#define NR 12288
#define DIMS 256
#define NCHUNK 8
#define CW (NR / NCHUNK)   // 1536
#define BM 64
#define TOPP 9

typedef __attribute__((ext_vector_type(8))) short short8v;
typedef __attribute__((ext_vector_type(4))) float f32x4;

__device__ __forceinline__ unsigned short f2bf(float f) {
    unsigned int u = __float_as_uint(f);
    u += 0x7fffu + ((u >> 16) & 1u);   // round-to-nearest-even
    return (unsigned short)(u >> 16);
}

// Maintain the 9 largest seen. Static indexing only (rule #20).
__device__ __forceinline__ void top9_insert(float (&a)[9], float& mn, float v) {
    if (v > mn) {
        bool done = false;
#pragma unroll
        for (int k = 0; k < 9; ++k) {
            bool hit = (!done) && (a[k] == mn);
            if (hit) a[k] = v;
            done = done || hit;
        }
        float m = a[0];
#pragma unroll
        for (int k = 1; k < 9; ++k) m = fminf(m, a[k]);
        mn = m;
    }
}

// ---------- 1) row-normalize fp32 -> bf16, one row per wave ----------
__global__ void k_norm(const float* __restrict__ x, unsigned short* __restrict__ emb) {
    const int wave = threadIdx.x >> 6, lane = threadIdx.x & 63;
    const int row = blockIdx.x * 4 + wave;
    const float4 v = *(const float4*)(x + (size_t)row * DIMS + lane * 4);
    float ss = v.x * v.x + v.y * v.y + v.z * v.z + v.w * v.w;
#pragma unroll
    for (int off = 32; off > 0; off >>= 1) ss += __shfl_xor(ss, off);
    const float inv = 1.0f / fmaxf(sqrtf(ss), 1e-12f);
    ushort4 o;
    o.x = f2bf(v.x * inv); o.y = f2bf(v.y * inv);
    o.z = f2bf(v.z * inv); o.w = f2bf(v.w * inv);
    *(ushort4*)(emb + (size_t)row * DIMS + lane * 4) = o;
}

// Shared GEMM micro-tile: 16 rows x 64 cols per wave-iteration, 4 independent
// acc chains. K-order per chain is fixed (kk=0..7) -> bit-identical sim in
// both passes regardless of scheduling.
#define GEMM_TILE4(B0, B1, B2, B3)                                            \
    f32x4 acc0 = {0.f, 0.f, 0.f, 0.f}, acc1 = {0.f, 0.f, 0.f, 0.f},           \
          acc2 = {0.f, 0.f, 0.f, 0.f}, acc3 = {0.f, 0.f, 0.f, 0.f};           \
    _Pragma("unroll")                                                          \
    for (int kk = 0; kk < 8; ++kk) {                                           \
        short8v bF0 = *(const short8v*)(B0 + kk * 32);                         \
        short8v bF1 = *(const short8v*)(B1 + kk * 32);                         \
        short8v bF2 = *(const short8v*)(B2 + kk * 32);                         \
        short8v bF3 = *(const short8v*)(B3 + kk * 32);                         \
        acc0 = __builtin_amdgcn_mfma_f32_16x16x32_bf16(aF[kk], bF0, acc0, 0, 0, 0); \
        acc1 = __builtin_amdgcn_mfma_f32_16x16x32_bf16(aF[kk], bF1, acc1, 0, 0, 0); \
        acc2 = __builtin_amdgcn_mfma_f32_16x16x32_bf16(aF[kk], bF2, acc2, 0, 0, 0); \
        acc3 = __builtin_amdgcn_mfma_f32_16x16x32_bf16(aF[kk], bF3, acc3, 0, 0, 0); \
    }

// ---------- 2) GEMM pass 1: per-row top-9 over a column chunk ----------
__global__ __launch_bounds__(256) void k_pass1(const unsigned short* __restrict__ emb,
                                               float* __restrict__ t9p) {
    const int bid = blockIdx.x;
    const int chunk = bid & 7, rb = bid >> 3;        // chunk -> XCD locality
    const int wave = threadIdx.x >> 6, lane = threadIdx.x & 63;
    const int l15 = lane & 15, lg = lane >> 4;
    const int R0 = rb * BM + wave * 16;

    short8v aF[8];
    const unsigned short* abase = emb + (size_t)(R0 + l15) * DIMS + lg * 8;
#pragma unroll
    for (int kk = 0; kk < 8; ++kk) aF[kk] = *(const short8v*)(abase + kk * 32);

    float t9[4][9];
    float tmin[4];
#pragma unroll
    for (int r = 0; r < 4; ++r) {
        tmin[r] = -3e38f;
#pragma unroll
        for (int k = 0; k < 9; ++k) t9[r][k] = -3e38f;
    }

    const int Cb = chunk * CW;
    const unsigned short* bbase = emb + (size_t)(Cb + l15) * DIMS + lg * 8;
    for (int ct = 0; ct < CW / 64; ++ct) {
        const unsigned short* b0 = bbase + (size_t)(ct * 64) * DIMS;
        const unsigned short* b1 = b0 + 16 * DIMS;
        const unsigned short* b2 = b0 + 32 * DIMS;
        const unsigned short* b3 = b0 + 48 * DIMS;
        GEMM_TILE4(b0, b1, b2, b3)
#pragma unroll
        for (int r = 0; r < 4; ++r) {
            top9_insert(t9[r], tmin[r], acc0[r]);
            top9_insert(t9[r], tmin[r], acc1[r]);
            top9_insert(t9[r], tmin[r], acc2[r]);
            top9_insert(t9[r], tmin[r], acc3[r]);
        }
    }

    // merge per-row over the 16 lanes sharing that row
    __shared__ float lt9[4][64][4][9];   // 36864 B
#pragma unroll
    for (int r = 0; r < 4; ++r)
#pragma unroll
        for (int k = 0; k < 9; ++k) lt9[wave][lane][r][k] = t9[r][k];
    __syncthreads();

    if (threadIdx.x < BM) {
        const int rl = threadIdx.x;
        const int w = rl >> 4, rin = rl & 15, g = rin >> 2, reg = rin & 3;
        float best[9], bmin = -3e38f;
#pragma unroll
        for (int k = 0; k < 9; ++k) best[k] = -3e38f;
        for (int s = 0; s < 16; ++s)
#pragma unroll
            for (int k = 0; k < 9; ++k) top9_insert(best, bmin, lt9[w][g * 16 + s][reg][k]);
        float* dst = t9p + ((size_t)(rb * BM + rl) * NCHUNK + chunk) * TOPP;
#pragma unroll
        for (int k = 0; k < 9; ++k) dst[k] = best[k];
    }
}

// ---------- 3) merge chunk top-9s -> per-row threshold (9th largest) ----------
__global__ void k_thr(const float* __restrict__ t9p, float* __restrict__ thr) {
    const int row = blockIdx.x * 256 + threadIdx.x;
    float best[9], bmin = -3e38f;
#pragma unroll
    for (int k = 0; k < 9; ++k) best[k] = -3e38f;
    const float* src = t9p + (size_t)row * NCHUNK * TOPP;
    for (int c = 0; c < NCHUNK * TOPP; ++c) top9_insert(best, bmin, src[c]);
    thr[row] = bmin;
}

// ---------- 4) GEMM pass 2 (bit-identical sim): out-deg + in-deg counts ----------
__global__ __launch_bounds__(256) void k_pass2(const unsigned short* __restrict__ emb,
                                               const float* __restrict__ thr,
                                               unsigned* __restrict__ dd,
                                               unsigned* __restrict__ gg) {
    const int bid = blockIdx.x;
    const int chunk = bid & 7, rb = bid >> 3;
    const int wave = threadIdx.x >> 6, lane = threadIdx.x & 63;
    const int l15 = lane & 15, lg = lane >> 4;
    const int R0 = rb * BM + wave * 16;

    __shared__ unsigned colcnt[CW];     // 6 KB: in-degree counts for this chunk
    __shared__ unsigned degp[BM];       // out-degree counts for this block's rows
    for (int i = threadIdx.x; i < CW; i += 256) colcnt[i] = 0;
    if (threadIdx.x < BM) degp[threadIdx.x] = 0;
    __syncthreads();

    short8v aF[8];
    const unsigned short* abase = emb + (size_t)(R0 + l15) * DIMS + lg * 8;
#pragma unroll
    for (int kk = 0; kk < 8; ++kk) aF[kk] = *(const short8v*)(abase + kk * 32);

    float thrv[4];
#pragma unroll
    for (int r = 0; r < 4; ++r) thrv[r] = thr[R0 + lg * 4 + r];

    const int Cb = chunk * CW;
    const unsigned short* bbase = emb + (size_t)(Cb + l15) * DIMS + lg * 8;
    for (int ct = 0; ct < CW / 64; ++ct) {
        const unsigned short* b0 = bbase + (size_t)(ct * 64) * DIMS;
        const unsigned short* b1 = b0 + 16 * DIMS;
        const unsigned short* b2 = b0 + 32 * DIMS;
        const unsigned short* b3 = b0 + 48 * DIMS;
        GEMM_TILE4(b0, b1, b2, b3)
        const int rloc = wave * 16 + lg * 4;
        const int cloc = ct * 64 + l15;
#pragma unroll
        for (int r = 0; r < 4; ++r) {
            const int rg = R0 + lg * 4 + r;
            if (acc0[r] >= thrv[r] && (Cb + cloc)      != rg) { atomicAdd(&degp[rloc + r], 1u); atomicAdd(&colcnt[cloc],      1u); }
            if (acc1[r] >= thrv[r] && (Cb + cloc + 16) != rg) { atomicAdd(&degp[rloc + r], 1u); atomicAdd(&colcnt[cloc + 16], 1u); }
            if (acc2[r] >= thrv[r] && (Cb + cloc + 32) != rg) { atomicAdd(&degp[rloc + r], 1u); atomicAdd(&colcnt[cloc + 32], 1u); }
            if (acc3[r] >= thrv[r] && (Cb + cloc + 48) != rg) { atomicAdd(&degp[rloc + r], 1u); atomicAdd(&colcnt[cloc + 48], 1u); }
        }
    }
    __syncthreads();
    if (threadIdx.x < BM) {
        unsigned c = degp[threadIdx.x];
        if (c) atomicAdd(&dd[rb * BM + threadIdx.x], c);
    }
    for (int i = threadIdx.x; i < CW; i += 256) {
        unsigned c = colcnt[i];
        if (c) atomicAdd(&gg[Cb + i], c);
    }
}

// ---------- 5) wsum = sum_i o*d + g*d - 2o, d = max(o,1)  (integer, determ.) ----------
__global__ void k_wsum(const unsigned* __restrict__ dd, const unsigned* __restrict__ gg,
                       unsigned long long* __restrict__ wsum) {
    const int i = blockIdx.x * 256 + threadIdx.x;
    const unsigned long long o = dd[i];
    const unsigned long long g = gg[i];
    const unsigned long long d = o ? o : 1ull;
    unsigned long long acc = o * d + g * d - 2ull * o;
#pragma unroll
    for (int off = 32; off > 0; off >>= 1) acc += __shfl_xor(acc, off);
    if ((threadIdx.x & 63) == 0 && acc) atomicAdd(wsum, acc);
}

// ---------- 6) finalize ----------
__global__ void k_fin(const unsigned long long* __restrict__ wsum, float* __restrict__ out) {
    out[0] = (float)((double)*wsum * (0.01 / ((double)NR * (double)NR)));
}

extern "C" void kernel_launch(void* const* d_in, const int* in_sizes, int n_in,
                              void* d_out, int out_size, void* d_ws, size_t ws_size,
                              hipStream_t stream) {
    const float* x = (const float*)d_in[0];
    float* out = (float*)d_out;
    char* ws = (char*)d_ws;

    size_t off = 0;
    unsigned short* emb = (unsigned short*)(ws + off); off += (size_t)NR * DIMS * 2;         // 6.29 MB
    float* t9p = (float*)(ws + off);                  off += (size_t)NR * NCHUNK * TOPP * 4; // 3.54 MB
    float* thr = (float*)(ws + off);                  off += (size_t)NR * 4;
    unsigned* dd = (unsigned*)(ws + off);             off += (size_t)NR * 4;
    unsigned* gg = (unsigned*)(ws + off);             off += (size_t)NR * 4;
    unsigned long long* wsum = (unsigned long long*)(ws + off);

    hipMemsetAsync(dd, 0, (size_t)NR * 4, stream);
    hipMemsetAsync(gg, 0, (size_t)NR * 4, stream);
    hipMemsetAsync(wsum, 0, 8, stream);

    k_norm<<<NR / 4, 256, 0, stream>>>(x, emb);
    k_pass1<<<NR / BM * NCHUNK, 256, 0, stream>>>(emb, t9p);
    k_thr<<<NR / 256, 256, 0, stream>>>(t9p, thr);
    k_pass2<<<NR / BM * NCHUNK, 256, 0, stream>>>(emb, thr, dd, gg);
    k_wsum<<<NR / 256, 256, 0, stream>>>(dd, gg, wsum);
    k_fin<<<1, 1, 0, stream>>>(wsum, out);
}